// Round 5
// baseline (327.719 us; speedup 1.0000x reference)
//
#include <hip/hip_runtime.h>
#include <hip/hip_bf16.h>
#include <cstdint>

#define SS 4096
#define DD 1024

typedef __attribute__((ext_vector_type(4))) float f32x4;
typedef __attribute__((ext_vector_type(8))) short bf16x8;

__device__ __forceinline__ float bf2f(unsigned short u) {
    union { unsigned int i; float f; } v; v.i = ((unsigned int)u) << 16; return v.f;
}
__device__ __forceinline__ unsigned short f2bf(float f) {
    union { float f; unsigned int i; } v; v.f = f;
    unsigned int r = v.i + 0x7fff + ((v.i >> 16) & 1);  // round-nearest-even
    return (unsigned short)(r >> 16);
}

// ---------------- batched fp32 -> bf16 cast (z selects tensor) ----------------
__global__ void cast3_f32_bf16(const float* __restrict__ q, const float* __restrict__ k,
                               const float* __restrict__ v,
                               unsigned short* __restrict__ oq, unsigned short* __restrict__ ok,
                               unsigned short* __restrict__ ov) {
    const int z = blockIdx.z;
    const float* in = (z == 0) ? q : (z == 1) ? k : v;
    unsigned short* out = (z == 0) ? oq : (z == 1) ? ok : ov;
    int i = (blockIdx.x * blockDim.x + threadIdx.x) * 4;
    float4 val = *(const float4*)(in + i);
    ushort4 o;
    o.x = f2bf(val.x); o.y = f2bf(val.y); o.z = f2bf(val.z); o.w = f2bf(val.w);
    *(ushort4*)(out + i) = o;
}

// ---------------- batched W [K][N] fp32 -> Wt [N][K] bf16 transpose ----------------
__global__ void transpose3_w(const float* __restrict__ wq, const float* __restrict__ wk,
                             const float* __restrict__ wv,
                             unsigned short* __restrict__ oq, unsigned short* __restrict__ ok,
                             unsigned short* __restrict__ ov) {
    const int z = blockIdx.z;
    const float* in = (z == 0) ? wq : (z == 1) ? wk : wv;
    unsigned short* out = (z == 0) ? oq : (z == 1) ? ok : ov;
    __shared__ float tile[32][33];
    int tx = threadIdx.x, ty = threadIdx.y;           // (32, 8)
    int c0 = blockIdx.x * 32, r0 = blockIdx.y * 32;
#pragma unroll
    for (int i = 0; i < 4; ++i) {
        int r = r0 + ty + i * 8;
        tile[ty + i * 8][tx] = in[(size_t)r * DD + c0 + tx];
    }
    __syncthreads();
#pragma unroll
    for (int i = 0; i < 4; ++i) {
        int r = ty + i * 8;
        out[(size_t)(c0 + r) * DD + r0 + tx] = f2bf(tile[tx][r]);
    }
}

// ---------------- V [S][D] bf16, rowsum[S] -> Vst [D][S] bf16 = V^T / rowsum ----------------
__global__ void scale_transpose_v(const unsigned short* __restrict__ vin,
                                  const float* __restrict__ rowsum,
                                  unsigned short* __restrict__ out) {
    __shared__ float tile[32][33];
    int tx = threadIdx.x, ty = threadIdx.y;           // (32, 8)
    int d0 = blockIdx.x * 32, j0 = blockIdx.y * 32;
#pragma unroll
    for (int i = 0; i < 4; ++i) {
        int j = j0 + ty + i * 8;
        tile[ty + i * 8][tx] = bf2f(vin[(size_t)j * DD + d0 + tx]) * (1.0f / rowsum[j]);
    }
    __syncthreads();
#pragma unroll
    for (int i = 0; i < 4; ++i) {
        int d = ty + i * 8;
        out[(size_t)(d0 + d) * SS + j0 + tx] = f2bf(tile[tx][d]);
    }
}

// ================= 256x256 8-wave phase-split bf16 GEMM core =================
// C[256-tile] = A[M,K] @ Bt[N,K]^T over k in [k_begin, k_begin+k_len)
// 512 threads = 8 waves (2 M x 4 N), per-wave C = 128x64.
// LDS: double-buffered 256x64 tiles for A and B (128 KB), st_16x32 swizzle
// (linear global_load_lds dest + inverse-swizzled global source + swizzled read).
// MODE 0: C = acc + bias[col], store bf16
// MODE 1: C = exp(acc/1024), store bf16, atomicAdd row sums into rowsum[]
// MODE 3: atomicAdd fp32 into Cout (split-K partial)
template <int MODE>
__device__ __forceinline__ void gemm256_core(
        const unsigned short* __restrict__ A, const unsigned short* __restrict__ Bt,
        const float* __restrict__ bias, float* __restrict__ rowsum,
        void* __restrict__ Cout, int N, int K, int k_begin, int k_len,
        int bm, int bn) {
    __shared__ unsigned short As[2][256 * 64];
    __shared__ unsigned short Bs[2][256 * 64];

    const int t = threadIdx.x;          // 0..511
    const int l = t & 63;
    const int wid = t >> 6;             // 0..7
    const int wr = wid >> 2;            // 0..1  (M half of block tile)
    const int wc = wid & 3;             // 0..3  (N quarter of block tile)
    const int lr = l & 15;
    const int lk = (l >> 4) * 8;        // k elem offset within a 32-k step

    f32x4 acc[8][4] = {};

    const size_t a_base = (size_t)bm * 256 * K;
    const size_t b_base = (size_t)bn * 256 * K;

    // stage one half (128 rows x 64 k = 16 KB); 2 gload_lds / thread.
    // dest is LINEAR; source chunk pre-swizzled (involution) so swizzled reads
    // return logical data (rule #21).
    auto stage_half = [&](const unsigned short* __restrict__ G, size_t g_base,
                          unsigned short* L, int half, int k0) {
#pragma unroll
        for (int i = 0; i < 2; ++i) {
            const int idx = i * 512 + t;
            const int row = idx >> 3;                       // 0..127 within half
            const int ch  = idx & 7;                        // 16B chunk in 128B row
            const int sch = ch ^ (((row >> 2) & 1) << 1);   // st_16x32 inverse-src
            __builtin_amdgcn_global_load_lds(
                (const __attribute__((address_space(1))) void*)
                    (G + g_base + (size_t)(half * 128 + row) * K + k0 + sch * 8),
                (__attribute__((address_space(3))) void*)
                    (L + (half * 128 + row) * 64 + ch * 8),
                16, 0, 0);
        }
    };

    // swizzled 16B fragment read: byte ^= ((byte>>9)&1)<<5
    auto lds_frag = [&](const unsigned short* L, int row, int k) -> bf16x8 {
        int byte = (row * 64 + k) * 2;
        byte ^= ((byte >> 9) & 1) << 5;
        return *(const bf16x8*)((const char*)L + byte);
    };

    const int NT = k_len / 64;

    // prologue: fill buffer 0 completely, drain, align
    stage_half(A,  a_base, As[0], 0, k_begin);
    stage_half(A,  a_base, As[0], 1, k_begin);
    stage_half(Bt, b_base, Bs[0], 0, k_begin);
    stage_half(Bt, b_base, Bs[0], 1, k_begin);
    asm volatile("s_waitcnt vmcnt(0)" ::: "memory");
    __builtin_amdgcn_s_barrier();

    int cur = 0;
    const int ar0 = wr * 128;           // wave A-row base within block tile
    const int br0 = wc * 64;            // wave B-row base within block tile

    for (int kt = 0; kt < NT; ++kt) {
        const unsigned short* Ac = As[cur];
        const unsigned short* Bc = Bs[cur];
        bf16x8 a[4][2], b0[2][2], b1[2][2];

        // ---- phase 0: issue ALL next-tile stages (8 VMEM, in flight across
        // phases 0-3 = T4's counted-window); compute quadrant (mh=0, nh=0)
        if (kt + 1 < NT) {
            const int kn = k_begin + (kt + 1) * 64;
            unsigned short* An = As[cur ^ 1];
            unsigned short* Bn = Bs[cur ^ 1];
            stage_half(A,  a_base, An, 0, kn);
            stage_half(A,  a_base, An, 1, kn);
            stage_half(Bt, b_base, Bn, 0, kn);
            stage_half(Bt, b_base, Bn, 1, kn);
        }
#pragma unroll
        for (int m = 0; m < 4; ++m)
#pragma unroll
            for (int s = 0; s < 2; ++s)
                a[m][s] = lds_frag(Ac, ar0 + m * 16 + lr, s * 32 + lk);
#pragma unroll
        for (int n = 0; n < 2; ++n)
#pragma unroll
            for (int s = 0; s < 2; ++s)
                b0[n][s] = lds_frag(Bc, br0 + n * 16 + lr, s * 32 + lk);
        __builtin_amdgcn_s_barrier();
        __builtin_amdgcn_s_setprio(1);
#pragma unroll
        for (int m = 0; m < 4; ++m)
#pragma unroll
            for (int n = 0; n < 2; ++n)
#pragma unroll
                for (int s = 0; s < 2; ++s)
                    acc[m][n] = __builtin_amdgcn_mfma_f32_16x16x32_bf16(a[m][s], b0[n][s], acc[m][n], 0, 0, 0);
        __builtin_amdgcn_s_setprio(0);
        __builtin_amdgcn_s_barrier();

        // ---- phase 1: quadrant (0,1) — reuse a[], load B n-frags 2,3
#pragma unroll
        for (int n = 0; n < 2; ++n)
#pragma unroll
            for (int s = 0; s < 2; ++s)
                b1[n][s] = lds_frag(Bc, br0 + 32 + n * 16 + lr, s * 32 + lk);
        __builtin_amdgcn_s_barrier();
        __builtin_amdgcn_s_setprio(1);
#pragma unroll
        for (int m = 0; m < 4; ++m)
#pragma unroll
            for (int n = 0; n < 2; ++n)
#pragma unroll
                for (int s = 0; s < 2; ++s)
                    acc[m][2 + n] = __builtin_amdgcn_mfma_f32_16x16x32_bf16(a[m][s], b1[n][s], acc[m][2 + n], 0, 0, 0);
        __builtin_amdgcn_s_setprio(0);
        __builtin_amdgcn_s_barrier();

        // ---- phase 2: quadrant (1,0) — load A m-frags 4..7, reuse b0[]
#pragma unroll
        for (int m = 0; m < 4; ++m)
#pragma unroll
            for (int s = 0; s < 2; ++s)
                a[m][s] = lds_frag(Ac, ar0 + 64 + m * 16 + lr, s * 32 + lk);
        __builtin_amdgcn_s_barrier();
        __builtin_amdgcn_s_setprio(1);
#pragma unroll
        for (int m = 0; m < 4; ++m)
#pragma unroll
            for (int n = 0; n < 2; ++n)
#pragma unroll
                for (int s = 0; s < 2; ++s)
                    acc[4 + m][n] = __builtin_amdgcn_mfma_f32_16x16x32_bf16(a[m][s], b0[n][s], acc[4 + m][n], 0, 0, 0);
        __builtin_amdgcn_s_setprio(0);
        __builtin_amdgcn_s_barrier();

        // ---- phase 3: quadrant (1,1) — all regs resident; then drain own
        // stages (had ~3 phases of flight) and handoff-barrier the buffers
        __builtin_amdgcn_s_setprio(1);
#pragma unroll
        for (int m = 0; m < 4; ++m)
#pragma unroll
            for (int n = 0; n < 2; ++n)
#pragma unroll
                for (int s = 0; s < 2; ++s)
                    acc[4 + m][2 + n] = __builtin_amdgcn_mfma_f32_16x16x32_bf16(a[m][s], b1[n][s], acc[4 + m][2 + n], 0, 0, 0);
        __builtin_amdgcn_s_setprio(0);
        asm volatile("s_waitcnt vmcnt(0)" ::: "memory");
        __builtin_amdgcn_s_barrier();
        cur ^= 1;
    }

    // ---- epilogue: C/D layout col = lane&15, row = (lane>>4)*4 + r
    const int r0 = (l >> 4) * 4;
    const int cc = l & 15;
    const int growb = bm * 256 + wr * 128;
    const int gcolb = bn * 256 + wc * 64;
#pragma unroll
    for (int m = 0; m < 8; ++m) {
        const int grow = growb + m * 16 + r0;
        if (MODE == 1) {
            float rs[4] = {0.f, 0.f, 0.f, 0.f};
#pragma unroll
            for (int n = 0; n < 4; ++n) {
                const int gcol = gcolb + n * 16 + cc;
#pragma unroll
                for (int r = 0; r < 4; ++r) {
                    float e = __expf(acc[m][n][r] * (1.0f / 1024.0f));
                    rs[r] += e;
                    ((unsigned short*)Cout)[(size_t)(grow + r) * N + gcol] = f2bf(e);
                }
            }
#pragma unroll
            for (int r = 0; r < 4; ++r) {
                float v = rs[r];
                v += __shfl_xor(v, 1, 64);
                v += __shfl_xor(v, 2, 64);
                v += __shfl_xor(v, 4, 64);
                v += __shfl_xor(v, 8, 64);
                if (cc == 0) atomicAdd(&rowsum[grow + r], v);
            }
        } else {
#pragma unroll
            for (int n = 0; n < 4; ++n) {
                const int gcol = gcolb + n * 16 + cc;
#pragma unroll
                for (int r = 0; r < 4; ++r) {
                    float v = acc[m][n][r];
                    if (MODE == 0) {
                        v += bias[gcol];
                        ((unsigned short*)Cout)[(size_t)(grow + r) * N + gcol] = f2bf(v);
                    } else {
                        atomicAdd(&((float*)Cout)[(size_t)(grow + r) * N + gcol], v);
                    }
                }
            }
        }
    }
}

// 3 projections, one dispatch: grid (4, 16, 3) = 192 blocks.
__global__ __launch_bounds__(512, 2) void proj3(
        const unsigned short* __restrict__ Xq, const unsigned short* __restrict__ Xk,
        const unsigned short* __restrict__ Xv,
        const unsigned short* __restrict__ Wqt, const unsigned short* __restrict__ Wkt,
        const unsigned short* __restrict__ Wvt,
        const float* __restrict__ bq, const float* __restrict__ bk, const float* __restrict__ bv,
        unsigned short* __restrict__ Qb, unsigned short* __restrict__ Kb,
        unsigned short* __restrict__ Vb) {
    const int z = blockIdx.z;
    const unsigned short* A  = (z == 0) ? Xq  : (z == 1) ? Xk  : Xv;
    const unsigned short* Bt = (z == 0) ? Wqt : (z == 1) ? Wkt : Wvt;
    const float* bias        = (z == 0) ? bq  : (z == 1) ? bk  : bv;
    unsigned short* C        = (z == 0) ? Qb  : (z == 1) ? Kb  : Vb;
    gemm256_core<0>(A, Bt, bias, nullptr, C, DD, DD, 0, DD, blockIdx.y, blockIdx.x);
}

// scores + exp + rowsum: grid (16, 16) = 256 blocks.
__global__ __launch_bounds__(512, 2) void gemm_scores(
        const unsigned short* __restrict__ Qb, const unsigned short* __restrict__ Kb,
        float* __restrict__ rowsum, unsigned short* __restrict__ E) {
    gemm256_core<1>(Qb, Kb, nullptr, rowsum, E, SS, DD, 0, DD, blockIdx.y, blockIdx.x);
}

// out = E @ Vst^T, split-K=4, fp32 atomic accumulate: grid (4, 16, 4) = 256 blocks.
__global__ __launch_bounds__(512, 2) void gemm_out(
        const unsigned short* __restrict__ E, const unsigned short* __restrict__ Vst,
        float* __restrict__ out) {
    gemm256_core<3>(E, Vst, nullptr, nullptr, out, DD, SS, blockIdx.z * (SS / 4), SS / 4,
                    blockIdx.y, blockIdx.x);
}

extern "C" void kernel_launch(void* const* d_in, const int* in_sizes, int n_in,
                              void* d_out, int out_size, void* d_ws, size_t ws_size,
                              hipStream_t stream) {
    const float* query = (const float*)d_in[0];
    const float* key   = (const float*)d_in[1];
    const float* value = (const float*)d_in[2];
    const float* Wq    = (const float*)d_in[3];
    const float* bq    = (const float*)d_in[4];
    const float* Wk    = (const float*)d_in[5];
    const float* bk    = (const float*)d_in[6];
    const float* Wv    = (const float*)d_in[7];
    const float* bv    = (const float*)d_in[8];
    float* out = (float*)d_out;

    char* ws = (char*)d_ws;
    const size_t SD = (size_t)SS * DD;           // 4M elems
    const size_t DDsz = (size_t)DD * DD;         // 1M elems

    // phase-1 region [0, 32MB): X (24MB) + Wt (6MB); later overlaid by E (32MB)
    unsigned short* Xq  = (unsigned short*)ws;
    unsigned short* Xk  = Xq + SD;
    unsigned short* Xv  = Xk + SD;
    unsigned short* Wqt = Xv + SD;
    unsigned short* Wkt = Wqt + DDsz;
    unsigned short* Wvt = Wkt + DDsz;
    unsigned short* E   = (unsigned short*)ws;   // overlays X/W once they are dead
    unsigned short* Qb  = (unsigned short*)(ws + ((size_t)32 << 20));
    unsigned short* Kb  = Qb + SD;
    unsigned short* Vb  = Kb + SD;
    unsigned short* Vst = Vb + SD;
    float* rowsum = (float*)(ws + ((size_t)64 << 20));

    hipMemsetAsync(rowsum, 0, SS * sizeof(float), stream);
    hipMemsetAsync(out, 0, (size_t)SS * DD * sizeof(float), stream);  // split-K accumulator

    cast3_f32_bf16<<<dim3(SS * DD / 4 / 256, 1, 3), 256, 0, stream>>>(query, key, value, Xq, Xk, Xv);

    transpose3_w<<<dim3(32, 32, 3), dim3(32, 8), 0, stream>>>(Wq, Wk, Wv, Wqt, Wkt, Wvt);

    proj3<<<dim3(DD / 256, SS / 256, 3), 512, 0, stream>>>(Xq, Xk, Xv, Wqt, Wkt, Wvt,
                                                           bq, bk, bv, Qb, Kb, Vb);

    gemm_scores<<<dim3(SS / 256, SS / 256), 512, 0, stream>>>(Qb, Kb, rowsum, E);

    scale_transpose_v<<<dim3(DD / 32, SS / 32), dim3(32, 8), 0, stream>>>(Vb, rowsum, Vst);

    gemm_out<<<dim3(DD / 256, SS / 256, 4), 512, 0, stream>>>(E, Vst, out);
}

// Round 6
// 277.972 us; speedup vs baseline: 1.1790x; 1.1790x over previous
//
#include <hip/hip_runtime.h>
#include <hip/hip_bf16.h>
#include <cstdint>

#define SS 4096
#define DD 1024

typedef __attribute__((ext_vector_type(4))) float f32x4;
typedef __attribute__((ext_vector_type(8))) short bf16x8;

__device__ __forceinline__ float bf2f(unsigned short u) {
    union { unsigned int i; float f; } v; v.i = ((unsigned int)u) << 16; return v.f;
}
__device__ __forceinline__ unsigned short f2bf(float f) {
    union { float f; unsigned int i; } v; v.f = f;
    unsigned int r = v.i + 0x7fff + ((v.i >> 16) & 1);  // round-nearest-even
    return (unsigned short)(r >> 16);
}

// ---------------- batched fp32 -> bf16 cast (z selects tensor) ----------------
__global__ void cast3_f32_bf16(const float* __restrict__ q, const float* __restrict__ k,
                               const float* __restrict__ v,
                               unsigned short* __restrict__ oq, unsigned short* __restrict__ ok,
                               unsigned short* __restrict__ ov) {
    const int z = blockIdx.z;
    const float* in = (z == 0) ? q : (z == 1) ? k : v;
    unsigned short* out = (z == 0) ? oq : (z == 1) ? ok : ov;
    int i = (blockIdx.x * blockDim.x + threadIdx.x) * 4;
    float4 val = *(const float4*)(in + i);
    ushort4 o;
    o.x = f2bf(val.x); o.y = f2bf(val.y); o.z = f2bf(val.z); o.w = f2bf(val.w);
    *(ushort4*)(out + i) = o;
}

// ---------------- batched W [K][N] fp32 -> Wt [N][K] bf16 transpose ----------------
__global__ void transpose3_w(const float* __restrict__ wq, const float* __restrict__ wk,
                             const float* __restrict__ wv,
                             unsigned short* __restrict__ oq, unsigned short* __restrict__ ok,
                             unsigned short* __restrict__ ov) {
    const int z = blockIdx.z;
    const float* in = (z == 0) ? wq : (z == 1) ? wk : wv;
    unsigned short* out = (z == 0) ? oq : (z == 1) ? ok : ov;
    __shared__ float tile[32][33];
    int tx = threadIdx.x, ty = threadIdx.y;           // (32, 8)
    int c0 = blockIdx.x * 32, r0 = blockIdx.y * 32;
#pragma unroll
    for (int i = 0; i < 4; ++i) {
        int r = r0 + ty + i * 8;
        tile[ty + i * 8][tx] = in[(size_t)r * DD + c0 + tx];
    }
    __syncthreads();
#pragma unroll
    for (int i = 0; i < 4; ++i) {
        int r = ty + i * 8;
        out[(size_t)(c0 + r) * DD + r0 + tx] = f2bf(tile[tx][r]);
    }
}

// ---------------- V [S][D] bf16, rowsum[S] -> Vst [D][S] bf16 = V^T / rowsum ----------------
__global__ void scale_transpose_v(const unsigned short* __restrict__ vin,
                                  const float* __restrict__ rowsum,
                                  unsigned short* __restrict__ out) {
    __shared__ float tile[32][33];
    int tx = threadIdx.x, ty = threadIdx.y;           // (32, 8)
    int d0 = blockIdx.x * 32, j0 = blockIdx.y * 32;
#pragma unroll
    for (int i = 0; i < 4; ++i) {
        int j = j0 + ty + i * 8;
        tile[ty + i * 8][tx] = bf2f(vin[(size_t)j * DD + d0 + tx]) * (1.0f / rowsum[j]);
    }
    __syncthreads();
#pragma unroll
    for (int i = 0; i < 4; ++i) {
        int d = ty + i * 8;
        out[(size_t)(d0 + d) * SS + j0 + tx] = f2bf(tile[tx][d]);
    }
}

// ---------------- out += P (split-K reduce), float4 ----------------
__global__ void add_out(float* __restrict__ out, const float* __restrict__ P) {
    int i = (blockIdx.x * blockDim.x + threadIdx.x) * 4;
    float4 a = *(const float4*)(out + i);
    float4 b = *(const float4*)(P + i);
    a.x += b.x; a.y += b.y; a.z += b.z; a.w += b.w;
    *(float4*)(out + i) = a;
}

// ---------------- 2-phase double-buffered bf16 GEMM core ----------------
// C[128-tile] = A[M,K] @ Bt[N,K]^T over k in [k_begin, k_begin+k_len)
// MODE 0: C = acc + bias[col], store bf16
// MODE 1: C = exp(acc/1024), store bf16, atomicAdd row sums into rowsum[]
// MODE 2: C = acc, plain fp32 store
template <int MODE>
__device__ __forceinline__ void gemm_core(
        const unsigned short* __restrict__ A, const unsigned short* __restrict__ Bt,
        const float* __restrict__ bias, float* __restrict__ rowsum,
        void* __restrict__ Cout, int N, int K, int k_begin, int k_len,
        int bm, int bn) {
    __shared__ unsigned short As[2][128 * 32];
    __shared__ unsigned short Bs[2][128 * 32];

    const int t = threadIdx.x;
    const int l = t & 63;
    const int w = t >> 6;
    const int wm = w >> 1, wn = w & 1;      // 2x2 wave grid, each wave 64x64
    f32x4 acc[4][4] = {};

    const size_t a_base = (size_t)bm * 128 * K;
    const size_t b_base = (size_t)bn * 128 * K;
    const int lk = (l >> 4) * 8;            // k-offset within BK=32
    const int lr = l & 15;

    // async global -> LDS staging, 16B/lane, linear LDS layout [row][32]
    auto stage = [&](int b, int k0) {
#pragma unroll
        for (int i = 0; i < 2; ++i) {
            const int idx = i * 256 + t;    // covers 8 bf16 each
            const int row = idx >> 2;
            const int col = (idx & 3) * 8;
            __builtin_amdgcn_global_load_lds(
                (const __attribute__((address_space(1))) void*)(A + a_base + (size_t)row * K + k0 + col),
                (__attribute__((address_space(3))) void*)(&As[b][idx * 8]), 16, 0, 0);
            __builtin_amdgcn_global_load_lds(
                (const __attribute__((address_space(1))) void*)(Bt + b_base + (size_t)row * K + k0 + col),
                (__attribute__((address_space(3))) void*)(&Bs[b][idx * 8]), 16, 0, 0);
        }
    };

    const int k_end = k_begin + k_len;
    stage(0, k_begin);
    __syncthreads();                        // drains vmcnt(0): buf0 ready

    int cur = 0;
    for (int k0 = k_begin; k0 < k_end; k0 += 32) {
        if (k0 + 32 < k_end) stage(cur ^ 1, k0 + 32);   // prefetch overlaps compute below
        bf16x8 af[4], bfr[4];
#pragma unroll
        for (int m = 0; m < 4; ++m)
            af[m] = *(const bf16x8*)&As[cur][(wm * 64 + m * 16 + lr) * 32 + lk];
#pragma unroll
        for (int n = 0; n < 4; ++n)
            bfr[n] = *(const bf16x8*)&Bs[cur][(wn * 64 + n * 16 + lr) * 32 + lk];
#pragma unroll
        for (int m = 0; m < 4; ++m)
#pragma unroll
            for (int n = 0; n < 4; ++n)
                acc[m][n] = __builtin_amdgcn_mfma_f32_16x16x32_bf16(af[m], bfr[n], acc[m][n], 0, 0, 0);
        __syncthreads();                    // drains prefetch vmcnt + lgkm; next buf ready
        cur ^= 1;
    }

    // epilogue: C/D layout col = lane&15, row = (lane>>4)*4 + r
    const int r0 = (l >> 4) * 4;
    const int cc = l & 15;
#pragma unroll
    for (int m = 0; m < 4; ++m) {
        const int growb = bm * 128 + wm * 64 + m * 16 + r0;
        if (MODE == 1) {
            float rs[4] = {0.f, 0.f, 0.f, 0.f};
#pragma unroll
            for (int n = 0; n < 4; ++n) {
                const int gcol = bn * 128 + wn * 64 + n * 16 + cc;
#pragma unroll
                for (int r = 0; r < 4; ++r) {
                    float e = __expf(acc[m][n][r] * (1.0f / 1024.0f));
                    rs[r] += e;
                    ((unsigned short*)Cout)[(size_t)(growb + r) * N + gcol] = f2bf(e);
                }
            }
#pragma unroll
            for (int r = 0; r < 4; ++r) {
                float v = rs[r];
                v += __shfl_xor(v, 1, 64);
                v += __shfl_xor(v, 2, 64);
                v += __shfl_xor(v, 4, 64);
                v += __shfl_xor(v, 8, 64);
                if (cc == 0) atomicAdd(&rowsum[growb + r], v);
            }
        } else {
#pragma unroll
            for (int n = 0; n < 4; ++n) {
                const int gcol = bn * 128 + wn * 64 + n * 16 + cc;
#pragma unroll
                for (int r = 0; r < 4; ++r) {
                    float v = acc[m][n][r];
                    if (MODE == 0) {
                        v += bias[gcol];
                        ((unsigned short*)Cout)[(size_t)(growb + r) * N + gcol] = f2bf(v);
                    } else {
                        ((float*)Cout)[(size_t)(growb + r) * N + gcol] = v;
                    }
                }
            }
        }
    }
}

// 3 projections in one dispatch: z selects (X, Wt, bias, C). 768 blocks = 3/CU.
__global__ __launch_bounds__(256) void proj3(
        const unsigned short* __restrict__ Xq, const unsigned short* __restrict__ Xk,
        const unsigned short* __restrict__ Xv,
        const unsigned short* __restrict__ Wqt, const unsigned short* __restrict__ Wkt,
        const unsigned short* __restrict__ Wvt,
        const float* __restrict__ bq, const float* __restrict__ bk, const float* __restrict__ bv,
        unsigned short* __restrict__ Qb, unsigned short* __restrict__ Kb,
        unsigned short* __restrict__ Vb) {
    const int z = blockIdx.z;
    const unsigned short* A  = (z == 0) ? Xq  : (z == 1) ? Xk  : Xv;
    const unsigned short* Bt = (z == 0) ? Wqt : (z == 1) ? Wkt : Wvt;
    const float* bias        = (z == 0) ? bq  : (z == 1) ? bk  : bv;
    unsigned short* C        = (z == 0) ? Qb  : (z == 1) ? Kb  : Vb;
    gemm_core<0>(A, Bt, bias, nullptr, C, DD, DD, 0, DD, blockIdx.y, blockIdx.x);
}

// scores + exp + rowsum: 1024 blocks = 4/CU.
__global__ __launch_bounds__(256) void gemm_scores(
        const unsigned short* __restrict__ Qb, const unsigned short* __restrict__ Kb,
        float* __restrict__ rowsum, unsigned short* __restrict__ E) {
    gemm_core<1>(Qb, Kb, nullptr, rowsum, E, SS, DD, 0, DD, blockIdx.y, blockIdx.x);
}

// out = E @ Vst^T, split-K=2 into disjoint fp32 buffers (z=0 -> out, z=1 -> P).
// No atomics: plain stores; add_out folds P into out afterwards. 512 blocks = 2/CU.
__global__ __launch_bounds__(256) void gemm_out(
        const unsigned short* __restrict__ E, const unsigned short* __restrict__ Vst,
        float* __restrict__ out, float* __restrict__ P) {
    float* dst = (blockIdx.z == 0) ? out : P;
    gemm_core<2>(E, Vst, nullptr, nullptr, dst, DD, SS, blockIdx.z * (SS / 2), SS / 2,
                 blockIdx.y, blockIdx.x);
}

extern "C" void kernel_launch(void* const* d_in, const int* in_sizes, int n_in,
                              void* d_out, int out_size, void* d_ws, size_t ws_size,
                              hipStream_t stream) {
    const float* query = (const float*)d_in[0];
    const float* key   = (const float*)d_in[1];
    const float* value = (const float*)d_in[2];
    const float* Wq    = (const float*)d_in[3];
    const float* bq    = (const float*)d_in[4];
    const float* Wk    = (const float*)d_in[5];
    const float* bk    = (const float*)d_in[6];
    const float* Wv    = (const float*)d_in[7];
    const float* bv    = (const float*)d_in[8];
    float* out = (float*)d_out;

    char* ws = (char*)d_ws;
    const size_t SD = (size_t)SS * DD;           // 4M elems
    const size_t DDsz = (size_t)DD * DD;         // 1M elems

    // phase-1 region [0, 32MB): X (24MB) + Wt (6MB); later overlaid by E (32MB)
    unsigned short* Xq  = (unsigned short*)ws;
    unsigned short* Xk  = Xq + SD;
    unsigned short* Xv  = Xk + SD;
    unsigned short* Wqt = Xv + SD;
    unsigned short* Wkt = Wqt + DDsz;
    unsigned short* Wvt = Wkt + DDsz;
    unsigned short* E   = (unsigned short*)ws;   // overlays X/W once they are dead
    unsigned short* Qb  = (unsigned short*)(ws + ((size_t)32 << 20));
    unsigned short* Kb  = Qb + SD;
    unsigned short* Vb  = Kb + SD;
    unsigned short* Vst = Vb + SD;
    float* rowsum = (float*)(ws + ((size_t)64 << 20));
    // split-K partial: overlays Qb+Kb (dead after gemm_scores). 16MB fp32.
    float* P = (float*)(ws + ((size_t)32 << 20));

    hipMemsetAsync(rowsum, 0, SS * sizeof(float), stream);

    cast3_f32_bf16<<<dim3(SS * DD / 4 / 256, 1, 3), 256, 0, stream>>>(query, key, value, Xq, Xk, Xv);

    transpose3_w<<<dim3(32, 32, 3), dim3(32, 8), 0, stream>>>(Wq, Wk, Wv, Wqt, Wkt, Wvt);

    proj3<<<dim3(DD / 128, SS / 128, 3), 256, 0, stream>>>(Xq, Xk, Xv, Wqt, Wkt, Wvt,
                                                           bq, bk, bv, Qb, Kb, Vb);

    gemm_scores<<<dim3(SS / 128, SS / 128), 256, 0, stream>>>(Qb, Kb, rowsum, E);

    scale_transpose_v<<<dim3(DD / 32, SS / 32), dim3(32, 8), 0, stream>>>(Vb, rowsum, Vst);

    gemm_out<<<dim3(DD / 128, SS / 128, 2), 256, 0, stream>>>(E, Vst, out, P);

    add_out<<<SS * DD / 4 / 256, 256, 0, stream>>>(out, P);
}